// Round 1
// baseline (444.457 us; speedup 1.0000x reference)
//
#include <hip/hip_runtime.h>
#include <math.h>

#define B_ 4
#define N_ 250000
#define K_ 32
#define NB 8192   // negative histogram buckets (top 13 bits of float(quad))
#define PB 4096   // positive histogram buckets (top 12 bits)

// ws layout (float units):
//   [0    .. 1024)  per-(b,k) stats accum: {count, sumEmb xyz, sumSig xyz, sumSig2}
//   [1024 .. 1028)  seed_bg[B]
//   [1028 .. 1032)  seed_fg[B]
//   [1032 .. 1160)  lov[B*K]
//   [2048 .. 4096)  p05 params: per seg 16 floats {se3, t3, A, counts, validf, smooth, pad...}
//   byte 65536 ..   float4 emb4[B*N]  (16 MB)

__global__ __launch_bounds__(256) void k_stats(
    const float* __restrict__ off, const float* __restrict__ crd,
    const float* __restrict__ sig, const float* __restrict__ seed,
    const int* __restrict__ inst,
    float* __restrict__ acc, float* __restrict__ seed_bg,
    float4* __restrict__ emb4)
{
  __shared__ float sacc[K_ * 8];
  __shared__ float sbg;
  const int b = blockIdx.y;
  const int tid = threadIdx.x;
  for (int i = tid; i < K_ * 8; i += 256) sacc[i] = 0.f;
  if (tid == 0) sbg = 0.f;
  __syncthreads();

  for (int n = blockIdx.x * 256 + tid; n < N_; n += 256 * gridDim.x) {
    int idx = b * N_ + n;
    float ex = tanhf(off[idx * 3 + 0]) + crd[idx * 3 + 0];
    float ey = tanhf(off[idx * 3 + 1]) + crd[idx * 3 + 1];
    float ez = tanhf(off[idx * 3 + 2]) + crd[idx * 3 + 2];
    emb4[idx] = make_float4(ex, ey, ez, 0.f);
    int k = inst[idx];
    if (k >= 0) {
      float sx = sig[idx * 3 + 0], sy = sig[idx * 3 + 1], sz = sig[idx * 3 + 2];
      atomicAdd(&sacc[k * 8 + 0], 1.f);
      atomicAdd(&sacc[k * 8 + 1], ex);
      atomicAdd(&sacc[k * 8 + 2], ey);
      atomicAdd(&sacc[k * 8 + 3], ez);
      atomicAdd(&sacc[k * 8 + 4], sx);
      atomicAdd(&sacc[k * 8 + 5], sy);
      atomicAdd(&sacc[k * 8 + 6], sz);
      atomicAdd(&sacc[k * 8 + 7], sx * sx + sy * sy + sz * sz);
    } else {
      float s = 1.f / (1.f + __expf(-seed[idx]));
      atomicAdd(&sbg, s * s);
    }
  }
  __syncthreads();
  for (int i = tid; i < K_ * 8; i += 256) atomicAdd(&acc[b * K_ * 8 + i], sacc[i]);
  if (tid == 0) atomicAdd(&seed_bg[b], sbg);
}

__global__ void k_params(const float* __restrict__ acc, float* __restrict__ p05)
{
  int seg = threadIdx.x;  // 0..127 = b*K + k
  const float* a = &acc[seg * 8];
  float counts = a[0];
  float cnt = fmaxf(counts, 1.f);
  float inv = 1.f / cnt;
  float cx = a[1] * inv, cy = a[2] * inv, cz = a[3] * inv;
  float skx = a[4] * inv, sky = a[5] * inv, skz = a[6] * inv;
  float sex = expf(10.f * skx), sey = expf(10.f * sky), sez = expf(10.f * skz);
  float dev2 = a[7] - 2.f * (a[4] * skx + a[5] * sky + a[6] * skz)
             + counts * (skx * skx + sky * sky + skz * skz);
  float smooth = dev2 / (cnt * 3.f);
  float A = sex * cx * cx + sey * cy * cy + sez * cz * cz;
  float* o = &p05[seg * 16];
  o[0] = sex; o[1] = sey; o[2] = sez;
  o[3] = 2.f * sex * cx; o[4] = 2.f * sey * cy; o[5] = 2.f * sez * cz;
  o[6] = A; o[7] = counts; o[8] = (counts > 0.f) ? 1.f : 0.f; o[9] = smooth;
}

__device__ __forceinline__ void scan_excl(uint32_t* h, int n, uint32_t* wsum, int tid)
{
  const int chunk = n >> 10;        // 8 or 4
  const int base = tid * chunk;
  uint32_t vals[8];
  uint32_t s = 0;
  for (int i = 0; i < chunk; ++i) { vals[i] = h[base + i]; s += vals[i]; }
  uint32_t x = s;
  int lane = tid & 63;
  for (int d = 1; d < 64; d <<= 1) {
    uint32_t y = (uint32_t)__shfl_up((int)x, d, 64);
    if (lane >= d) x += y;
  }
  int wid = tid >> 6;
  if (lane == 63) wsum[wid] = x;
  __syncthreads();
  if (tid == 0) {
    uint32_t a = 0;
    for (int w = 0; w < 16; ++w) { uint32_t t = wsum[w]; wsum[w] = a; a += t; }
  }
  __syncthreads();
  uint32_t run = wsum[wid] + (x - s);   // exclusive prefix of this thread's chunk
  for (int i = 0; i < chunk; ++i) { uint32_t t = vals[i]; h[base + i] = run; run += t; }
  __syncthreads();
}

__global__ __launch_bounds__(1024) void k_lovasz(
    const int* __restrict__ inst, const float* __restrict__ seed,
    const float4* __restrict__ emb4, const float* __restrict__ p05,
    float* __restrict__ lov_out, float* __restrict__ seed_fg)
{
  __shared__ uint32_t hneg[NB];
  __shared__ uint32_t hpos[PB];
  __shared__ uint32_t wsum[16];
  __shared__ float red[32];

  const int seg = blockIdx.x;
  const int b = seg >> 5, k = seg & 31;
  const float* pp = &p05[seg * 16];
  const float sex = pp[0], sey = pp[1], sez = pp[2];
  const float tx = pp[3], ty = pp[4], tz = pp[5], A = pp[6];
  const float Gf = pp[7];
  const int tid = threadIdx.x;
  if (Gf <= 0.f) { if (tid == 0) lov_out[seg] = 0.f; return; }
  const float Nnegf = (float)N_ - Gf;
  const int base = b * N_;

  for (int i = tid; i < NB; i += 1024) hneg[i] = 0;
  for (int i = tid; i < PB; i += 1024) hpos[i] = 0;
  __syncthreads();

  // pass 1: histogram quads by class
  for (int n = tid; n < N_; n += 1024) {
    float4 e = emb4[base + n];
    float quad = e.x * (sex * e.x - tx) + e.y * (sey * e.y - ty)
               + e.z * (sez * e.z - tz) + A;
    quad = fmaxf(quad, 0.f);
    uint32_t bits = __float_as_uint(quad);
    if (inst[base + n] == k) atomicAdd(&hpos[bits >> 20], 1u);
    else                     atomicAdd(&hneg[bits >> 19], 1u);
  }
  __syncthreads();
  scan_excl(hneg, NB, wsum, tid);
  scan_excl(hpos, PB, wsum, tid);

  // pass 2: contributions
  float lov = 0.f, sfg = 0.f;
  for (int n = tid; n < N_; n += 1024) {
    float4 e = emb4[base + n];
    float quad = e.x * (sex * e.x - tx) + e.y * (sey * e.y - ty)
               + e.z * (sez * e.z - tz) + A;
    float qc = fmaxf(quad, 0.f);
    float p = __expf(-qc);               // p in (0,1]
    float qs = -__logf(1.f - p);         // threshold transform, in [0, +inf]
    uint32_t qb = __float_as_uint(qs);
    if (inst[base + n] == k) {
      float epos = 2.f - 2.f * p;
      uint32_t bk = qb >> 19;            // query neg scan: F = #neg with q < qs
      float frac = (float)(qb & 0x7FFFFu) * (1.f / 524288.f);
      float bc = (float)hneg[bk];
      float nx = (bk < NB - 1) ? (float)hneg[bk + 1] : Nnegf;
      float F = bc + frac * (nx - bc);
      lov += epos / (Gf + F);
      float s = 1.f / (1.f + __expf(-seed[base + n]));
      float d = s - p;
      sfg += d * d;
    } else if (p > 0.f) {
      float eneg = 2.f * p;
      uint32_t mb = __float_as_uint(qc) >> 19;   // own rank bucket among negatives
      float R = (float)hneg[mb];
      float nx = (mb < NB - 1) ? (float)hneg[mb + 1] : Nnegf;
      float m = nx - R;                          // >= 1
      float psi = 1.f / ((Gf + R) * (Gf + R + m));  // exact bucket-avg of telescoped grad
      uint32_t pbk = qb >> 20;           // query pos scan: C = #pos with q <= qs
      float frac = (float)(qb & 0xFFFFFu) * (1.f / 1048576.f);
      float bc = (float)hpos[pbk];
      float pn = (pbk < PB - 1) ? (float)hpos[pbk + 1] : Gf;
      float C = bc + frac * (pn - bc);
      lov += eneg * C * psi;
    }
  }

  // block reduce (wave shuffle, then 16 wave partials)
  for (int d = 32; d > 0; d >>= 1) {
    lov += __shfl_down(lov, d, 64);
    sfg += __shfl_down(sfg, d, 64);
  }
  int wid = tid >> 6, lane = tid & 63;
  if (lane == 0) { red[wid] = lov; red[16 + wid] = sfg; }
  __syncthreads();
  if (tid == 0) {
    float lt = 0.f, st = 0.f;
    for (int w = 0; w < 16; ++w) { lt += red[w]; st += red[16 + w]; }
    lov_out[seg] = lt;
    atomicAdd(&seed_fg[b], st);
  }
}

__global__ void k_final(const float* __restrict__ p05, const float* __restrict__ lov,
                        const float* __restrict__ seed_bg, const float* __restrict__ seed_fg,
                        float* __restrict__ out)
{
  float total = 0.f;
  for (int b = 0; b < B_; ++b) {
    float vsum = 0.f, lsum = 0.f, ssum = 0.f;
    for (int k = 0; k < K_; ++k) {
      int seg = b * K_ + k;
      float vf = p05[seg * 16 + 8];
      vsum += vf;
      lsum += lov[seg] * vf;
      ssum += p05[seg * 16 + 9] * vf;
    }
    float obj = fmaxf(vsum, 1.f);
    float seed_l = (seed_bg[b] + seed_fg[b]) / (float)N_;
    total += lsum / obj + 10.f * (ssum / obj) + 10.f * seed_l;
  }
  out[0] = total / (float)B_;
}

extern "C" void kernel_launch(void* const* d_in, const int* in_sizes, int n_in,
                              void* d_out, int out_size, void* d_ws, size_t ws_size,
                              hipStream_t stream) {
  const float* off  = (const float*)d_in[0];
  const float* crd  = (const float*)d_in[1];
  const float* sig  = (const float*)d_in[2];
  const float* seed = (const float*)d_in[3];
  const int*   inst = (const int*)d_in[4];

  float* ws      = (float*)d_ws;
  float* acc     = ws;            // 1024 floats
  float* seed_bg = ws + 1024;     // 4
  float* seed_fg = ws + 1028;     // 4
  float* lov     = ws + 1032;     // 128
  float* p05     = ws + 2048;     // 2048
  float4* emb4   = (float4*)((char*)d_ws + 65536);  // 16 MB

  hipMemsetAsync(d_ws, 0, 8192, stream);  // zero all atomics/accumulators

  dim3 g1(128, B_);
  k_stats<<<g1, 256, 0, stream>>>(off, crd, sig, seed, inst, acc, seed_bg, emb4);
  k_params<<<1, 128, 0, stream>>>(acc, p05);
  k_lovasz<<<B_ * K_, 1024, 0, stream>>>(inst, seed, emb4, p05, lov, seed_fg);
  k_final<<<1, 1, 0, stream>>>(p05, lov, seed_bg, seed_fg, (float*)d_out);
}

// Round 2
// 283.997 us; speedup vs baseline: 1.5650x; 1.5650x over previous
//
#include <hip/hip_runtime.h>
#include <math.h>

#define B_ 4
#define N_ 250000
#define K_ 32
#define NB 4096   // neg hist: bits>>19, max index 4080 (sign bit always 0)
#define PB 2048   // pos hist: bits>>20, max index 2040
#define S1 8      // hist split over N
#define S2 16     // pass2 split over N

// ws layout (float units):
//   [0    .. 1024)  per-(b,k) stats accum
//   [1024 .. 1028)  seed_bg[B]
//   [1028 .. 1032)  seed_fg[B]
//   [1032 .. 1160)  lov[B*K]
//   [2048 .. 4096)  p05 params: per seg 16 floats
//   byte 65536 ..             emb3[B*N*3] floats (12 MB)
//   byte 65536+12MB ..        hneg_g[128*4096] u32 (2 MB), hpos_g[128*2048] u32 (1 MB)

__device__ __forceinline__ float fast_tanh(float x) {
  // tanh(x) = 1 - 2/(exp(2x)+1)
  return 1.f - 2.f / (__expf(2.f * x) + 1.f);
}

__global__ __launch_bounds__(256) void k_stats(
    const float* __restrict__ off, const float* __restrict__ crd,
    const float* __restrict__ sig, const float* __restrict__ seed,
    const int* __restrict__ inst,
    float* __restrict__ acc, float* __restrict__ seed_bg,
    float* __restrict__ emb3)
{
  __shared__ float sacc[K_ * 8];
  __shared__ float sbg;
  const int b = blockIdx.y;
  const int tid = threadIdx.x;
  for (int i = tid; i < K_ * 8; i += 256) sacc[i] = 0.f;
  if (tid == 0) sbg = 0.f;
  __syncthreads();

  for (int n = blockIdx.x * 256 + tid; n < N_; n += 256 * gridDim.x) {
    int idx = b * N_ + n;
    float ex = fast_tanh(off[idx * 3 + 0]) + crd[idx * 3 + 0];
    float ey = fast_tanh(off[idx * 3 + 1]) + crd[idx * 3 + 1];
    float ez = fast_tanh(off[idx * 3 + 2]) + crd[idx * 3 + 2];
    emb3[idx * 3 + 0] = ex;
    emb3[idx * 3 + 1] = ey;
    emb3[idx * 3 + 2] = ez;
    int k = inst[idx];
    if (k >= 0) {
      float sx = sig[idx * 3 + 0], sy = sig[idx * 3 + 1], sz = sig[idx * 3 + 2];
      atomicAdd(&sacc[k * 8 + 0], 1.f);
      atomicAdd(&sacc[k * 8 + 1], ex);
      atomicAdd(&sacc[k * 8 + 2], ey);
      atomicAdd(&sacc[k * 8 + 3], ez);
      atomicAdd(&sacc[k * 8 + 4], sx);
      atomicAdd(&sacc[k * 8 + 5], sy);
      atomicAdd(&sacc[k * 8 + 6], sz);
      atomicAdd(&sacc[k * 8 + 7], sx * sx + sy * sy + sz * sz);
    } else {
      float s = 1.f / (1.f + __expf(-seed[idx]));
      atomicAdd(&sbg, s * s);
    }
  }
  __syncthreads();
  for (int i = tid; i < K_ * 8; i += 256) atomicAdd(&acc[b * K_ * 8 + i], sacc[i]);
  if (tid == 0) atomicAdd(&seed_bg[b], sbg);
}

__global__ void k_params(const float* __restrict__ acc, float* __restrict__ p05)
{
  int seg = threadIdx.x;  // 0..127
  const float* a = &acc[seg * 8];
  float counts = a[0];
  float cnt = fmaxf(counts, 1.f);
  float inv = 1.f / cnt;
  float cx = a[1] * inv, cy = a[2] * inv, cz = a[3] * inv;
  float skx = a[4] * inv, sky = a[5] * inv, skz = a[6] * inv;
  float sex = expf(10.f * skx), sey = expf(10.f * sky), sez = expf(10.f * skz);
  float dev2 = a[7] - 2.f * (a[4] * skx + a[5] * sky + a[6] * skz)
             + counts * (skx * skx + sky * sky + skz * skz);
  float smooth = dev2 / (cnt * 3.f);
  float A = sex * cx * cx + sey * cy * cy + sez * cz * cz;
  float* o = &p05[seg * 16];
  o[0] = sex; o[1] = sey; o[2] = sez;
  o[3] = 2.f * sex * cx; o[4] = 2.f * sey * cy; o[5] = 2.f * sez * cz;
  o[6] = A; o[7] = counts; o[8] = (counts > 0.f) ? 1.f : 0.f; o[9] = smooth;
}

// hist kernel: per (seg, chunk) block, LDS-private histograms, flush to global
__global__ __launch_bounds__(512) void k_hist(
    const int* __restrict__ inst, const float* __restrict__ emb3,
    const float* __restrict__ p05,
    uint32_t* __restrict__ hneg_g, uint32_t* __restrict__ hpos_g)
{
  __shared__ uint32_t h[NB + PB];
  const int seg = blockIdx.x >> 3;          // / S1
  const int chunk = blockIdx.x & (S1 - 1);
  const int b = seg >> 5, k = seg & 31;
  const float* pp = &p05[seg * 16];
  const float Gf = pp[7];
  if (Gf <= 0.f) return;
  const float sex = pp[0], sey = pp[1], sez = pp[2];
  const float tx = pp[3], ty = pp[4], tz = pp[5], A = pp[6];
  const int tid = threadIdx.x;
  const int base = b * N_;
  const int n0 = chunk * (N_ / S1);
  const int n1 = (chunk == S1 - 1) ? N_ : n0 + (N_ / S1);

  for (int i = tid; i < NB + PB; i += 512) h[i] = 0;
  __syncthreads();

  for (int n = n0 + tid; n < n1; n += 512) {
    float ex = emb3[(base + n) * 3 + 0];
    float ey = emb3[(base + n) * 3 + 1];
    float ez = emb3[(base + n) * 3 + 2];
    float quad = ex * (sex * ex - tx) + ey * (sey * ey - ty)
               + ez * (sez * ez - tz) + A;
    quad = fmaxf(quad, 0.f);
    uint32_t bits = __float_as_uint(quad);
    if (inst[base + n] == k) atomicAdd(&h[NB + (bits >> 20)], 1u);
    else                     atomicAdd(&h[bits >> 19], 1u);
  }
  __syncthreads();
  uint32_t* gn = &hneg_g[seg * NB];
  uint32_t* gp = &hpos_g[seg * PB];
  for (int i = tid; i < NB; i += 512) { uint32_t v = h[i]; if (v) atomicAdd(&gn[i], v); }
  for (int i = tid; i < PB; i += 512) { uint32_t v = h[NB + i]; if (v) atomicAdd(&gp[i], v); }
}

__device__ __forceinline__ void scan_excl(uint32_t* h, int n, uint32_t* wsum, int tid)
{
  const int chunk = n >> 10;        // 4 or 2 (1024 threads)
  const int base = tid * chunk;
  uint32_t vals[4];
  uint32_t s = 0;
  for (int i = 0; i < chunk; ++i) { vals[i] = h[base + i]; s += vals[i]; }
  uint32_t x = s;
  int lane = tid & 63;
  for (int d = 1; d < 64; d <<= 1) {
    uint32_t y = (uint32_t)__shfl_up((int)x, d, 64);
    if (lane >= d) x += y;
  }
  int wid = tid >> 6;
  if (lane == 63) wsum[wid] = x;
  __syncthreads();
  if (tid == 0) {
    uint32_t a = 0;
    for (int w = 0; w < 16; ++w) { uint32_t t = wsum[w]; wsum[w] = a; a += t; }
  }
  __syncthreads();
  uint32_t run = wsum[wid] + (x - s);
  for (int i = 0; i < chunk; ++i) { uint32_t t = vals[i]; h[base + i] = run; run += t; }
  __syncthreads();
}

__global__ __launch_bounds__(1024) void k_scan(
    const float* __restrict__ p05,
    uint32_t* __restrict__ hneg_g, uint32_t* __restrict__ hpos_g)
{
  __shared__ uint32_t h[NB + PB];
  __shared__ uint32_t wsum[16];
  const int seg = blockIdx.x;
  const float Gf = p05[seg * 16 + 7];
  if (Gf <= 0.f) return;
  const int tid = threadIdx.x;
  uint32_t* gn = &hneg_g[seg * NB];
  uint32_t* gp = &hpos_g[seg * PB];
  for (int i = tid; i < NB; i += 1024) h[i] = gn[i];
  for (int i = tid; i < PB; i += 1024) h[NB + i] = gp[i];
  __syncthreads();
  scan_excl(h, NB, wsum, tid);
  scan_excl(h + NB, PB, wsum, tid);
  for (int i = tid; i < NB; i += 1024) gn[i] = h[i];
  for (int i = tid; i < PB; i += 1024) gp[i] = h[NB + i];
}

__global__ __launch_bounds__(256) void k_pass2(
    const int* __restrict__ inst, const float* __restrict__ seed,
    const float* __restrict__ emb3, const float* __restrict__ p05,
    const uint32_t* __restrict__ hneg_g, const uint32_t* __restrict__ hpos_g,
    float* __restrict__ lov_out, float* __restrict__ seed_fg)
{
  __shared__ float red[32];
  const int seg = blockIdx.x >> 4;          // / S2
  const int chunk = blockIdx.x & (S2 - 1);
  const int b = seg >> 5, k = seg & 31;
  const float* pp = &p05[seg * 16];
  const float Gf = pp[7];
  if (Gf <= 0.f) return;
  const float sex = pp[0], sey = pp[1], sez = pp[2];
  const float tx = pp[3], ty = pp[4], tz = pp[5], A = pp[6];
  const float Nnegf = (float)N_ - Gf;
  const int tid = threadIdx.x;
  const int base = b * N_;
  const int n0 = chunk * (N_ / S2);
  const int n1 = (chunk == S2 - 1) ? N_ : n0 + (N_ / S2);
  const uint32_t* hneg = &hneg_g[seg * NB];
  const uint32_t* hpos = &hpos_g[seg * PB];

  float lov = 0.f, sfg = 0.f;
  for (int n = n0 + tid; n < n1; n += 256) {
    float ex = emb3[(base + n) * 3 + 0];
    float ey = emb3[(base + n) * 3 + 1];
    float ez = emb3[(base + n) * 3 + 2];
    float quad = ex * (sex * ex - tx) + ey * (sey * ey - ty)
               + ez * (sez * ez - tz) + A;
    float qc = fmaxf(quad, 0.f);
    float p = __expf(-qc);               // p in (0,1]
    float qs = -__logf(1.f - p);         // threshold transform
    uint32_t qb = __float_as_uint(qs);
    if (inst[base + n] == k) {
      float epos = 2.f - 2.f * p;
      uint32_t bk = qb >> 19;            // F = #neg with q < qs
      if (bk > NB - 1) bk = NB - 1;
      float frac = (float)(qb & 0x7FFFFu) * (1.f / 524288.f);
      float bc = (float)hneg[bk];
      float nx = (bk < NB - 1) ? (float)hneg[bk + 1] : Nnegf;
      float F = bc + frac * (nx - bc);
      lov += epos / (Gf + F);
      float s = 1.f / (1.f + __expf(-seed[base + n]));
      float d = s - p;
      sfg += d * d;
    } else if (p > 0.f) {
      float eneg = 2.f * p;
      uint32_t mb = __float_as_uint(qc) >> 19;   // own bucket among negatives
      float R = (float)hneg[mb];
      float nx = (mb < NB - 1) ? (float)hneg[mb + 1] : Nnegf;
      float m = nx - R;
      float psi = 1.f / ((Gf + R) * (Gf + R + m));  // exact bucket-avg grad
      uint32_t pbk = qb >> 20;           // C = #pos with q <= qs
      if (pbk > PB - 1) pbk = PB - 1;
      float frac = (float)(qb & 0xFFFFFu) * (1.f / 1048576.f);
      float bc = (float)hpos[pbk];
      float pn = (pbk < PB - 1) ? (float)hpos[pbk + 1] : Gf;
      float C = bc + frac * (pn - bc);
      lov += eneg * C * psi;
    }
  }

  for (int d = 32; d > 0; d >>= 1) {
    lov += __shfl_down(lov, d, 64);
    sfg += __shfl_down(sfg, d, 64);
  }
  int wid = tid >> 6, lane = tid & 63;
  if (lane == 0) { red[wid] = lov; red[16 + wid] = sfg; }
  __syncthreads();
  if (tid == 0) {
    float lt = 0.f, st = 0.f;
    for (int w = 0; w < 4; ++w) { lt += red[w]; st += red[16 + w]; }
    atomicAdd(&lov_out[seg], lt);
    atomicAdd(&seed_fg[b], st);
  }
}

__global__ void k_final(const float* __restrict__ p05, const float* __restrict__ lov,
                        const float* __restrict__ seed_bg, const float* __restrict__ seed_fg,
                        float* __restrict__ out)
{
  __shared__ float sv[B_], sl[B_], ss[B_];
  int tid = threadIdx.x;   // 128 threads = one per seg
  if (tid < B_) { sv[tid] = 0.f; sl[tid] = 0.f; ss[tid] = 0.f; }
  __syncthreads();
  int b = tid >> 5;
  float vf = p05[tid * 16 + 8];
  atomicAdd(&sv[b], vf);
  atomicAdd(&sl[b], lov[tid] * vf);
  atomicAdd(&ss[b], p05[tid * 16 + 9] * vf);
  __syncthreads();
  if (tid == 0) {
    float total = 0.f;
    for (int bb = 0; bb < B_; ++bb) {
      float obj = fmaxf(sv[bb], 1.f);
      float seed_l = (seed_bg[bb] + seed_fg[bb]) / (float)N_;
      total += sl[bb] / obj + 10.f * (ss[bb] / obj) + 10.f * seed_l;
    }
    out[0] = total / (float)B_;
  }
}

extern "C" void kernel_launch(void* const* d_in, const int* in_sizes, int n_in,
                              void* d_out, int out_size, void* d_ws, size_t ws_size,
                              hipStream_t stream) {
  const float* off  = (const float*)d_in[0];
  const float* crd  = (const float*)d_in[1];
  const float* sig  = (const float*)d_in[2];
  const float* seed = (const float*)d_in[3];
  const int*   inst = (const int*)d_in[4];

  float* ws      = (float*)d_ws;
  float* acc     = ws;            // 1024 floats
  float* seed_bg = ws + 1024;     // 4
  float* seed_fg = ws + 1028;     // 4
  float* lov     = ws + 1032;     // 128
  float* p05     = ws + 2048;     // 2048
  float* emb3    = (float*)((char*)d_ws + 65536);                 // 12 MB
  uint32_t* hneg_g = (uint32_t*)((char*)d_ws + 65536 + 12000000); // 2 MB
  uint32_t* hpos_g = hneg_g + 128 * NB;                           // 1 MB

  hipMemsetAsync(d_ws, 0, 8192, stream);
  hipMemsetAsync(hneg_g, 0, 128 * (NB + PB) * 4, stream);

  dim3 g1(128, B_);
  k_stats<<<g1, 256, 0, stream>>>(off, crd, sig, seed, inst, acc, seed_bg, emb3);
  k_params<<<1, 128, 0, stream>>>(acc, p05);
  k_hist<<<B_ * K_ * S1, 512, 0, stream>>>(inst, emb3, p05, hneg_g, hpos_g);
  k_scan<<<B_ * K_, 1024, 0, stream>>>(p05, hneg_g, hpos_g);
  k_pass2<<<B_ * K_ * S2, 256, 0, stream>>>(inst, seed, emb3, p05, hneg_g, hpos_g, lov, seed_fg);
  k_final<<<1, 128, 0, stream>>>(p05, lov, seed_bg, seed_fg, (float*)d_out);
}

// Round 3
// 259.085 us; speedup vs baseline: 1.7155x; 1.0962x over previous
//
#include <hip/hip_runtime.h>
#include <math.h>

#define B_ 4
#define N_ 250000
#define K_ 32
#define NB 4096   // buckets for bits>>19; any nonneg float maps to <=4080
#define S1 8      // hist split over N
#define S2 16     // pass2 split over N

// ws layout (bytes):
//   0        .. 8192       small accums: acc[1024]f, seed_bg[4], seed_fg[4], lov[128], p05 @ float 2048
//   65536    .. +16MB      emb4[B*N] float4 {ex,ey,ez,(float)inst}
//   +16MB    .. +2MB       hneg_g[128*4096] u32   (hist over qc of negatives)
//   ..       .. +2MB       hpos_g[128*4096] u32   (hist over qs of positives)
//   ..       .. +8MB       tabN[128*4096] float4  {posLE_base, posLE_delta, 2*psi_avg, 0}
//   ..       .. +4MB       tabP[128*4096] float2  {negLT_base, negLT_delta}

__device__ __forceinline__ float fast_tanh(float x) {
  return 1.f - 2.f / (__expf(2.f * x) + 1.f);
}

__global__ __launch_bounds__(256) void k_stats(
    const float* __restrict__ off, const float* __restrict__ crd,
    const float* __restrict__ sig, const float* __restrict__ seed,
    const int* __restrict__ inst,
    float* __restrict__ acc, float* __restrict__ seed_bg,
    float4* __restrict__ emb4)
{
  __shared__ float sacc[K_ * 8];
  __shared__ float sbg;
  const int b = blockIdx.y;
  const int tid = threadIdx.x;
  for (int i = tid; i < K_ * 8; i += 256) sacc[i] = 0.f;
  if (tid == 0) sbg = 0.f;
  __syncthreads();

  for (int n = blockIdx.x * 256 + tid; n < N_; n += 256 * gridDim.x) {
    int idx = b * N_ + n;
    float ex = fast_tanh(off[idx * 3 + 0]) + crd[idx * 3 + 0];
    float ey = fast_tanh(off[idx * 3 + 1]) + crd[idx * 3 + 1];
    float ez = fast_tanh(off[idx * 3 + 2]) + crd[idx * 3 + 2];
    int k = inst[idx];
    emb4[idx] = make_float4(ex, ey, ez, (float)k);
    if (k >= 0) {
      float sx = sig[idx * 3 + 0], sy = sig[idx * 3 + 1], sz = sig[idx * 3 + 2];
      atomicAdd(&sacc[k * 8 + 0], 1.f);
      atomicAdd(&sacc[k * 8 + 1], ex);
      atomicAdd(&sacc[k * 8 + 2], ey);
      atomicAdd(&sacc[k * 8 + 3], ez);
      atomicAdd(&sacc[k * 8 + 4], sx);
      atomicAdd(&sacc[k * 8 + 5], sy);
      atomicAdd(&sacc[k * 8 + 6], sz);
      atomicAdd(&sacc[k * 8 + 7], sx * sx + sy * sy + sz * sz);
    } else {
      float s = 1.f / (1.f + __expf(-seed[idx]));
      atomicAdd(&sbg, s * s);
    }
  }
  __syncthreads();
  for (int i = tid; i < K_ * 8; i += 256) atomicAdd(&acc[b * K_ * 8 + i], sacc[i]);
  if (tid == 0) atomicAdd(&seed_bg[b], sbg);
}

__global__ void k_params(const float* __restrict__ acc, float* __restrict__ p05)
{
  int seg = threadIdx.x;  // 0..127
  const float* a = &acc[seg * 8];
  float counts = a[0];
  float cnt = fmaxf(counts, 1.f);
  float inv = 1.f / cnt;
  float cx = a[1] * inv, cy = a[2] * inv, cz = a[3] * inv;
  float skx = a[4] * inv, sky = a[5] * inv, skz = a[6] * inv;
  float sex = expf(10.f * skx), sey = expf(10.f * sky), sez = expf(10.f * skz);
  float dev2 = a[7] - 2.f * (a[4] * skx + a[5] * sky + a[6] * skz)
             + counts * (skx * skx + sky * sky + skz * skz);
  float smooth = dev2 / (cnt * 3.f);
  float A = sex * cx * cx + sey * cy * cy + sez * cz * cz;
  float* o = &p05[seg * 16];
  o[0] = sex; o[1] = sey; o[2] = sez;
  o[3] = 2.f * sex * cx; o[4] = 2.f * sey * cy; o[5] = 2.f * sez * cz;
  o[6] = A; o[7] = counts; o[8] = (counts > 0.f) ? 1.f : 0.f; o[9] = smooth;
}

// hist: neg by qc bits, pos by qs=-log(1-p) bits (log only on ~3% positives)
__global__ __launch_bounds__(512) void k_hist(
    const float4* __restrict__ emb4, const float* __restrict__ p05,
    uint32_t* __restrict__ hneg_g, uint32_t* __restrict__ hpos_g)
{
  __shared__ uint32_t h[2 * NB];
  const int seg = blockIdx.x >> 3;          // / S1
  const int chunk = blockIdx.x & (S1 - 1);
  const int b = seg >> 5, k = seg & 31;
  const float* pp = &p05[seg * 16];
  const float Gf = pp[7];
  if (Gf <= 0.f) return;
  const float sex = pp[0], sey = pp[1], sez = pp[2];
  const float tx = pp[3], ty = pp[4], tz = pp[5], A = pp[6];
  const float kf = (float)k;
  const int tid = threadIdx.x;
  const int base = b * N_;
  const int n0 = chunk * (N_ / S1);
  const int n1 = (chunk == S1 - 1) ? N_ : n0 + (N_ / S1);

  for (int i = tid; i < 2 * NB; i += 512) h[i] = 0;
  __syncthreads();

  for (int n = n0 + tid; n < n1; n += 512) {
    float4 e = emb4[base + n];
    float quad = e.x * (sex * e.x - tx) + e.y * (sey * e.y - ty)
               + e.z * (sez * e.z - tz) + A;
    float qc = fmaxf(quad, 0.f);
    if (e.w == kf) {
      float p = __expf(-qc);
      float qs = -__logf(1.f - p);        // p==1 -> inf -> bucket 4080, fine
      atomicAdd(&h[NB + (__float_as_uint(qs) >> 19)], 1u);
    } else {
      atomicAdd(&h[__float_as_uint(qc) >> 19], 1u);
    }
  }
  __syncthreads();
  uint32_t* gn = &hneg_g[seg * NB];
  uint32_t* gp = &hpos_g[seg * NB];
  for (int i = tid; i < NB; i += 512) { uint32_t v = h[i];      if (v) atomicAdd(&gn[i], v); }
  for (int i = tid; i < NB; i += 512) { uint32_t v = h[NB + i]; if (v) atomicAdd(&gp[i], v); }
}

__device__ __forceinline__ void scan_excl(uint32_t* h, uint32_t* wsum, int tid)
{
  const int chunk = NB >> 10;  // 4
  const int base = tid * chunk;
  uint32_t vals[4];
  uint32_t s = 0;
  for (int i = 0; i < chunk; ++i) { vals[i] = h[base + i]; s += vals[i]; }
  uint32_t x = s;
  int lane = tid & 63;
  for (int d = 1; d < 64; d <<= 1) {
    uint32_t y = (uint32_t)__shfl_up((int)x, d, 64);
    if (lane >= d) x += y;
  }
  int wid = tid >> 6;
  if (lane == 63) wsum[wid] = x;
  __syncthreads();
  if (tid == 0) {
    uint32_t a = 0;
    for (int w = 0; w < 16; ++w) { uint32_t t = wsum[w]; wsum[w] = a; a += t; }
  }
  __syncthreads();
  uint32_t run = wsum[wid] + (x - s);
  for (int i = 0; i < chunk; ++i) { uint32_t t = vals[i]; h[base + i] = run; run += t; }
  __syncthreads();
}

__global__ __launch_bounds__(1024) void k_scan(
    const float* __restrict__ p05,
    const uint32_t* __restrict__ hneg_g, const uint32_t* __restrict__ hpos_g,
    float4* __restrict__ tabN, float2* __restrict__ tabP)
{
  __shared__ uint32_t hn[NB];
  __shared__ uint32_t hp[NB];
  __shared__ uint32_t wsum[16];
  const int seg = blockIdx.x;
  const float Gf = p05[seg * 16 + 7];
  if (Gf <= 0.f) return;
  const float Nnegf = (float)N_ - Gf;
  const int tid = threadIdx.x;
  const uint32_t* gn = &hneg_g[seg * NB];
  const uint32_t* gp = &hpos_g[seg * NB];
  for (int i = tid; i < NB; i += 1024) { hn[i] = gn[i]; hp[i] = gp[i]; }
  __syncthreads();
  scan_excl(hn, wsum, tid);
  scan_excl(hp, wsum, tid);
  float4* tN = &tabN[(size_t)seg * NB];
  float2* tP = &tabP[(size_t)seg * NB];
  for (int bkt = tid; bkt < NB; bkt += 1024) {
    float pb = (float)hp[bkt];
    float pn = (bkt < NB - 1) ? (float)hp[bkt + 1] : Gf;
    float R  = (float)hn[bkt];
    float nn = (bkt < NB - 1) ? (float)hn[bkt + 1] : Nnegf;
    float m  = nn - R;
    float gr = Gf + R;
    float psi2 = 2.f / (gr * (gr + m));   // 2 * bucket-avg telescoped grad
    tN[bkt] = make_float4(pb, pn - pb, psi2, 0.f);
    tP[bkt] = make_float2(R, m);
  }
}

__global__ __launch_bounds__(256) void k_pass2(
    const float* __restrict__ seed,
    const float4* __restrict__ emb4, const float* __restrict__ p05,
    const float4* __restrict__ tabN, const float2* __restrict__ tabP,
    float* __restrict__ lov_out, float* __restrict__ seed_fg)
{
  __shared__ float red[32];
  const int seg = blockIdx.x >> 4;          // / S2
  const int chunk = blockIdx.x & (S2 - 1);
  const int b = seg >> 5, k = seg & 31;
  const float* pp = &p05[seg * 16];
  const float Gf = pp[7];
  if (Gf <= 0.f) return;
  const float sex = pp[0], sey = pp[1], sez = pp[2];
  const float tx = pp[3], ty = pp[4], tz = pp[5], A = pp[6];
  const float kf = (float)k;
  const int tid = threadIdx.x;
  const int base = b * N_;
  const int n0 = chunk * (N_ / S2);
  const int n1 = (chunk == S2 - 1) ? N_ : n0 + (N_ / S2);
  const float4* tN = &tabN[(size_t)seg * NB];
  const float2* tP = &tabP[(size_t)seg * NB];

  float lov = 0.f, sfg = 0.f;
  for (int n = n0 + tid; n < n1; n += 256) {
    float4 e = emb4[base + n];
    float quad = e.x * (sex * e.x - tx) + e.y * (sey * e.y - ty)
               + e.z * (sez * e.z - tz) + A;
    float qc = fmaxf(quad, 0.f);
    float p = __expf(-qc);
    if (e.w == kf) {
      // positive: F = #neg with qc_j < qs_i (neg table, key qs)
      float qs = -__logf(1.f - p);
      uint32_t qb = __float_as_uint(qs);
      float frac = (float)(qb & 0x7FFFFu) * (1.f / 524288.f);
      float2 tp = tP[qb >> 19];
      float F = tp.x + frac * tp.y;
      lov += (2.f - 2.f * p) / (Gf + F);
      float s = 1.f / (1.f + __expf(-seed[base + n]));
      float d = s - p;
      sfg += d * d;
    } else {
      // negative: C = #pos with e+ < e-  = Gf - #pos{qs <= qc_j}; contrib = 2p*C*psi
      uint32_t cb = __float_as_uint(qc);
      float frac = (float)(cb & 0x7FFFFu) * (1.f / 524288.f);
      float4 t = tN[cb >> 19];
      float Cle = t.x + frac * t.y;
      lov += p * (Gf - Cle) * t.z;        // t.z = 2*psi_avg
    }
  }

  for (int d = 32; d > 0; d >>= 1) {
    lov += __shfl_down(lov, d, 64);
    sfg += __shfl_down(sfg, d, 64);
  }
  int wid = tid >> 6, lane = tid & 63;
  if (lane == 0) { red[wid] = lov; red[16 + wid] = sfg; }
  __syncthreads();
  if (tid == 0) {
    float lt = 0.f, st = 0.f;
    for (int w = 0; w < 4; ++w) { lt += red[w]; st += red[16 + w]; }
    atomicAdd(&lov_out[seg], lt);
    atomicAdd(&seed_fg[b], st);
  }
}

__global__ void k_final(const float* __restrict__ p05, const float* __restrict__ lov,
                        const float* __restrict__ seed_bg, const float* __restrict__ seed_fg,
                        float* __restrict__ out)
{
  __shared__ float sv[B_], sl[B_], ss[B_];
  int tid = threadIdx.x;   // 128 threads, one per seg
  if (tid < B_) { sv[tid] = 0.f; sl[tid] = 0.f; ss[tid] = 0.f; }
  __syncthreads();
  int b = tid >> 5;
  float vf = p05[tid * 16 + 8];
  atomicAdd(&sv[b], vf);
  atomicAdd(&sl[b], lov[tid] * vf);
  atomicAdd(&ss[b], p05[tid * 16 + 9] * vf);
  __syncthreads();
  if (tid == 0) {
    float total = 0.f;
    for (int bb = 0; bb < B_; ++bb) {
      float obj = fmaxf(sv[bb], 1.f);
      float seed_l = (seed_bg[bb] + seed_fg[bb]) / (float)N_;
      total += sl[bb] / obj + 10.f * (ss[bb] / obj) + 10.f * seed_l;
    }
    out[0] = total / (float)B_;
  }
}

extern "C" void kernel_launch(void* const* d_in, const int* in_sizes, int n_in,
                              void* d_out, int out_size, void* d_ws, size_t ws_size,
                              hipStream_t stream) {
  const float* off  = (const float*)d_in[0];
  const float* crd  = (const float*)d_in[1];
  const float* sig  = (const float*)d_in[2];
  const float* seed = (const float*)d_in[3];
  const int*   inst = (const int*)d_in[4];

  float* ws      = (float*)d_ws;
  float* acc     = ws;            // 1024 floats
  float* seed_bg = ws + 1024;     // 4
  float* seed_fg = ws + 1028;     // 4
  float* lov     = ws + 1032;     // 128
  float* p05     = ws + 2048;     // byte 8192, 2048 floats
  char* pbase = (char*)d_ws;
  float4*   emb4   = (float4*)(pbase + 65536);                     // 16 MB
  uint32_t* hneg_g = (uint32_t*)(pbase + 65536 + 16000000);        // 2 MB
  uint32_t* hpos_g = hneg_g + 128 * NB;                            // 2 MB
  float4*   tabN   = (float4*)(pbase + 65536 + 16000000 + 4194304);// 8 MB
  float2*   tabP   = (float2*)((char*)tabN + 8388608);             // 4 MB

  hipMemsetAsync(d_ws, 0, 8192, stream);
  hipMemsetAsync(hneg_g, 0, 2 * 128 * NB * 4, stream);

  dim3 g1(128, B_);
  k_stats<<<g1, 256, 0, stream>>>(off, crd, sig, seed, inst, acc, seed_bg, emb4);
  k_params<<<1, 128, 0, stream>>>(acc, p05);
  k_hist<<<B_ * K_ * S1, 512, 0, stream>>>(emb4, p05, hneg_g, hpos_g);
  k_scan<<<B_ * K_, 1024, 0, stream>>>(p05, hneg_g, hpos_g, tabN, tabP);
  k_pass2<<<B_ * K_ * S2, 256, 0, stream>>>(seed, emb4, p05, tabN, tabP, lov, seed_fg);
  k_final<<<1, 128, 0, stream>>>(p05, lov, seed_bg, seed_fg, (float*)d_out);
}